// Round 1
// baseline (721.022 us; speedup 1.0000x reference)
//
#include <hip/hip_runtime.h>
#include <math.h>

#define NZ   128
#define H1   512
#define H2   1024
#define IMG  784
#define BATCH 4096
#define NGEN 10

// ---------------- bucket samples by generator ----------------
__global__ void bucket_kernel(const int* __restrict__ g_idx,
                              int* __restrict__ counts,
                              int* __restrict__ lists) {
    int b = blockIdx.x * blockDim.x + threadIdx.x;
    if (b < BATCH) {
        int g = g_idx[b];
        int pos = atomicAdd(&counts[g], 1);
        lists[g * BATCH + pos] = b;
    }
}

// ---------------- grouped GEMM layer ----------------
// C[s][:] = act(A[s][:] @ W[g] + bias[g]) for samples s in bucket g.
// Tile: 64 (M) x 64 (N), K-chunks of 16, 256 threads, 4x4 per thread.
// ACT: 0 = relu, 1 = tanh
template<int K, int N, int ACT>
__global__ __launch_bounds__(256)
void mlp_layer(const float* __restrict__ A,     // [BATCH][K] indexed by sample id
               const float* __restrict__ W,     // [NGEN][K][N]
               const float* __restrict__ bias,  // [NGEN][N]
               float* __restrict__ C,           // [BATCH][N] indexed by sample id
               const int* __restrict__ counts,
               const int* __restrict__ lists) {
    const int g  = blockIdx.z;
    const int ng = counts[g];
    const int row0 = blockIdx.x * 64;
    if (row0 >= ng) return;                 // uniform per block: safe early exit
    const int n0 = blockIdx.y * 64;

    // padded leading dim 68: write-conflict ~2-way (free), reads 16B-aligned
    __shared__ float As[16 * 68];           // As[k][m]
    __shared__ float Bs[16 * 68];           // Bs[k][n]

    const int tid = threadIdx.x;
    const int tx = tid & 15;                // n-quad: cols n0 + tx*4 .. +3
    const int ty = tid >> 4;                // m-quad: rows row0 + ty*4 .. +3

    // --- staging roles ---
    // A: thread -> (row r = tid>>2, k-quad q = tid&3)
    const int ar = tid >> 2;
    const int aq = tid & 3;
    const int a_row_clamped = min(row0 + ar, ng - 1);
    const int s_a = lists[g * BATCH + a_row_clamped];
    const float* a_src = A + (size_t)s_a * K + aq * 4;
    // B: thread -> (k row bk = tid>>4, n-quad bq = tid&15)
    const int bk = tid >> 4;
    const int bq = (tid & 15) * 4;
    const int bcol = n0 + bq;
    const float* w_base = W + (size_t)g * K * N + (size_t)bk * N + bcol;

    float acc[4][4];
    #pragma unroll
    for (int i = 0; i < 4; ++i)
        #pragma unroll
        for (int j = 0; j < 4; ++j) acc[i][j] = 0.f;

    for (int k0 = 0; k0 < K; k0 += 16) {
        // load A chunk: 64 rows x 16 k
        float4 av = *(const float4*)(a_src + k0);
        // load B chunk: 16 k x 64 n (guard cols for N=784 tail)
        float4 bv = make_float4(0.f, 0.f, 0.f, 0.f);
        if (bcol < N) bv = *(const float4*)(w_base + (size_t)k0 * N);
        __syncthreads();
        As[(aq * 4 + 0) * 68 + ar] = av.x;
        As[(aq * 4 + 1) * 68 + ar] = av.y;
        As[(aq * 4 + 2) * 68 + ar] = av.z;
        As[(aq * 4 + 3) * 68 + ar] = av.w;
        *(float4*)&Bs[bk * 68 + bq] = bv;
        __syncthreads();

        #pragma unroll
        for (int kk = 0; kk < 16; ++kk) {
            float4 a = *(const float4*)&As[kk * 68 + ty * 4];
            float4 b = *(const float4*)&Bs[kk * 68 + tx * 4];
            const float af[4] = {a.x, a.y, a.z, a.w};
            const float bf[4] = {b.x, b.y, b.z, b.w};
            #pragma unroll
            for (int i = 0; i < 4; ++i)
                #pragma unroll
                for (int j = 0; j < 4; ++j)
                    acc[i][j] = fmaf(af[i], bf[j], acc[i][j]);
        }
    }

    // --- epilogue: bias + activation + scatter store ---
    const int col0 = n0 + tx * 4;
    float4 bv = make_float4(0.f, 0.f, 0.f, 0.f);
    if (col0 < N) bv = *(const float4*)&bias[(size_t)g * N + col0];
    const float bf[4] = {bv.x, bv.y, bv.z, bv.w};

    #pragma unroll
    for (int i = 0; i < 4; ++i) {
        int gr = row0 + ty * 4 + i;
        if (gr < ng && col0 < N) {
            int s = lists[g * BATCH + gr];
            float4 v;
            float* vp = (float*)&v;
            #pragma unroll
            for (int j = 0; j < 4; ++j) {
                float x = acc[i][j] + bf[j];
                vp[j] = (ACT == 0) ? fmaxf(x, 0.f) : tanhf(x);
            }
            *(float4*)&C[(size_t)s * N + col0] = v;
        }
    }
}

extern "C" void kernel_launch(void* const* d_in, const int* in_sizes, int n_in,
                              void* d_out, int out_size, void* d_ws, size_t ws_size,
                              hipStream_t stream) {
    const float* z    = (const float*)d_in[0];
    const int*   gidx = (const int*)  d_in[1];
    const float* W1   = (const float*)d_in[2];
    const float* b1   = (const float*)d_in[3];
    const float* W2   = (const float*)d_in[4];
    const float* b2   = (const float*)d_in[5];
    const float* W3   = (const float*)d_in[6];
    const float* b3   = (const float*)d_in[7];
    float* out = (float*)d_out;

    char* ws = (char*)d_ws;
    int*   counts = (int*)ws;                                  // 64 B
    int*   lists  = (int*)(ws + 1024);                         // 160 KB
    float* h1     = (float*)(ws + 262144);                     // 8 MB
    float* h2     = (float*)(ws + 262144 + (size_t)BATCH * H1 * 4); // 16 MB

    hipMemsetAsync(counts, 0, 64, stream);
    bucket_kernel<<<dim3(BATCH / 256), dim3(256), 0, stream>>>(gidx, counts, lists);

    mlp_layer<NZ, H1, 0><<<dim3(BATCH / 64, H1 / 64, NGEN), dim3(256), 0, stream>>>(
        z, W1, b1, h1, counts, lists);
    mlp_layer<H1, H2, 0><<<dim3(BATCH / 64, H2 / 64, NGEN), dim3(256), 0, stream>>>(
        h1, W2, b2, h2, counts, lists);
    mlp_layer<H2, IMG, 1><<<dim3(BATCH / 64, (IMG + 63) / 64, NGEN), dim3(256), 0, stream>>>(
        h2, W3, b3, out, counts, lists);
}

// Round 2
// 430.922 us; speedup vs baseline: 1.6732x; 1.6732x over previous
//
#include <hip/hip_runtime.h>
#include <math.h>

#define NZ    128
#define H1    512
#define H2    1024
#define IMG   784
#define IMGP  832      // IMG padded to multiple of 64 for guard-free B staging
#define BATCH 4096
#define NGEN  10

typedef __attribute__((ext_vector_type(8))) short short8;
typedef __attribute__((ext_vector_type(4))) float floatx4;

__device__ __forceinline__ unsigned short f2bf(float x) {   // RNE fp32 -> bf16
    unsigned u = __float_as_uint(x);
    u += 0x7fff + ((u >> 16) & 1);
    return (unsigned short)(u >> 16);
}
__device__ __forceinline__ float bf2f(unsigned short h) {
    return __uint_as_float(((unsigned)h) << 16);
}

// ---------------- bucket samples by generator ----------------
__global__ void bucket_kernel(const int* __restrict__ g_idx,
                              int* __restrict__ counts,
                              int* __restrict__ lists) {
    int b = blockIdx.x * blockDim.x + threadIdx.x;
    if (b < BATCH) {
        int g = g_idx[b];
        int pos = atomicAdd(&counts[g], 1);
        lists[g * BATCH + pos] = b;
    }
}

// ---------------- split activations (z) into hi/lo bf16 planes ----------------
template<bool SPLIT>
__global__ void split_act(const float* __restrict__ x, unsigned short* __restrict__ hi,
                          unsigned short* __restrict__ lo, int n) {
    int i = blockIdx.x * 256 + threadIdx.x;
    if (i < n) {
        float v = x[i];
        unsigned short h = f2bf(v);
        hi[i] = h;
        if (SPLIT) lo[i] = f2bf(v - bf2f(h));
    }
}

// ---------------- transpose + split weights: [g][K][N] f32 -> [g][NPAD][K] bf16 hi/lo ----------------
template<int K, int N, int NPAD, bool SPLIT>
__global__ __launch_bounds__(256)
void transpose_split(const float* __restrict__ W, unsigned short* __restrict__ Whi,
                     unsigned short* __restrict__ Wlo) {
    const int g  = blockIdx.z;
    const int k0 = blockIdx.x * 32;
    const int n0 = blockIdx.y * 32;
    __shared__ unsigned short Lh[32][36];   // [n_local][k_local], stride 36 for 8B-aligned quads
    __shared__ unsigned short Ll[32][36];
    const int t = threadIdx.x;
    {
        const int kk = t >> 3;
        const int nq = (t & 7) * 4;
        float4 v = make_float4(0.f, 0.f, 0.f, 0.f);
        if (n0 + nq < N)   // N % 4 == 0 so quads never straddle the edge
            v = *(const float4*)(W + ((size_t)g * K + (k0 + kk)) * N + n0 + nq);
        const float vv[4] = {v.x, v.y, v.z, v.w};
        #pragma unroll
        for (int j = 0; j < 4; ++j) {
            unsigned short h = f2bf(vv[j]);
            Lh[nq + j][kk] = h;
            if (SPLIT) Ll[nq + j][kk] = f2bf(vv[j] - bf2f(h));
        }
    }
    __syncthreads();
    {
        const int nn = t >> 3;
        const int kq = (t & 7) * 4;
        size_t o = ((size_t)g * NPAD + (n0 + nn)) * K + k0 + kq;
        *(ushort4*)(Whi + o) = *(const ushort4*)&Lh[nn][kq];
        if (SPLIT) *(ushort4*)(Wlo + o) = *(const ushort4*)&Ll[nn][kq];
    }
}

// ---------------- grouped split-bf16 MFMA GEMM layer ----------------
// C[s] = act(A[s] @ W[g] + bias[g]) via Ahi*Bhi + Ahi*Blo + Alo*Bhi (SPLIT).
// Block: 256 thr = 4 waves; tile 64M x 64N; wave tile 32x32 (2x2 of 16x16); BK=32.
template<int K, int NOUT, int NPADB, int ACT, bool SPLIT, bool OUTF32>
__global__ __launch_bounds__(256)
void gemm_mfma(const unsigned short* __restrict__ Ahi, const unsigned short* __restrict__ Alo,
               const unsigned short* __restrict__ Bhi, const unsigned short* __restrict__ Blo,
               const float* __restrict__ bias,
               unsigned short* __restrict__ Chi, unsigned short* __restrict__ Clo,
               float* __restrict__ Cf,
               const int* __restrict__ counts, const int* __restrict__ lists) {
    const int g  = blockIdx.z;
    const int ng = counts[g];
    const int row0 = blockIdx.x * 64;
    if (row0 >= ng) return;                 // block-uniform early exit
    const int n0 = blockIdx.y * 64;

    // stride 40 ushort (80B) rows: b128 accesses cover all 32 banks uniformly
    __shared__ unsigned short Ash[64 * 40];
    __shared__ unsigned short Als[64 * 40];
    __shared__ unsigned short Bsh[64 * 40];
    __shared__ unsigned short Bls[64 * 40];

    const int tid = threadIdx.x;
    // staging roles: row r (m for A / n for B), k-quad q (8 bf16 = 16B)
    const int r = tid >> 2, q = tid & 3;
    const int gr_a = min(row0 + r, ng - 1);
    const int s_a  = lists[g * BATCH + gr_a];
    const unsigned short* a_hi_src = Ahi + (size_t)s_a * K + q * 8;
    const unsigned short* a_lo_src = SPLIT ? (Alo + (size_t)s_a * K + q * 8) : Ahi;
    const unsigned short* b_hi_src = Bhi + ((size_t)g * NPADB + n0 + r) * K + q * 8;
    const unsigned short* b_lo_src = SPLIT ? (Blo + ((size_t)g * NPADB + n0 + r) * K + q * 8) : Bhi;
    const int lds_off = r * 40 + q * 8;

    // compute roles: wave w covers m-half mh, n-half nh; 16x16 MFMA lane mapping
    const int lane = tid & 63, w = tid >> 6;
    const int mh = (w & 1) * 32, nh = (w >> 1) * 32;
    const int lm = lane & 15, lq = lane >> 4;

    floatx4 acc[2][2] = {};

    for (int k0 = 0; k0 < K; k0 += 32) {
        short8 av_h = *(const short8*)(a_hi_src + k0);
        short8 bv_h = *(const short8*)(b_hi_src + k0);
        short8 av_l, bv_l;
        if (SPLIT) {
            av_l = *(const short8*)(a_lo_src + k0);
            bv_l = *(const short8*)(b_lo_src + k0);
        }
        __syncthreads();
        *(short8*)&Ash[lds_off] = av_h;
        *(short8*)&Bsh[lds_off] = bv_h;
        if (SPLIT) {
            *(short8*)&Als[lds_off] = av_l;
            *(short8*)&Bls[lds_off] = bv_l;
        }
        __syncthreads();

        short8 ah[2], bh[2], al[2], bl[2];
        #pragma unroll
        for (int mt = 0; mt < 2; ++mt) {
            ah[mt] = *(const short8*)&Ash[(mh + mt * 16 + lm) * 40 + lq * 8];
            if (SPLIT) al[mt] = *(const short8*)&Als[(mh + mt * 16 + lm) * 40 + lq * 8];
        }
        #pragma unroll
        for (int nt = 0; nt < 2; ++nt) {
            bh[nt] = *(const short8*)&Bsh[(nh + nt * 16 + lm) * 40 + lq * 8];
            if (SPLIT) bl[nt] = *(const short8*)&Bls[(nh + nt * 16 + lm) * 40 + lq * 8];
        }
        #pragma unroll
        for (int mt = 0; mt < 2; ++mt)
            #pragma unroll
            for (int nt = 0; nt < 2; ++nt) {
                acc[mt][nt] = __builtin_amdgcn_mfma_f32_16x16x32_bf16(ah[mt], bh[nt], acc[mt][nt], 0, 0, 0);
                if (SPLIT) {
                    acc[mt][nt] = __builtin_amdgcn_mfma_f32_16x16x32_bf16(ah[mt], bl[nt], acc[mt][nt], 0, 0, 0);
                    acc[mt][nt] = __builtin_amdgcn_mfma_f32_16x16x32_bf16(al[mt], bh[nt], acc[mt][nt], 0, 0, 0);
                }
            }
    }

    // epilogue: C/D layout col = lane&15, row = (lane>>4)*4 + reg
    #pragma unroll
    for (int mt = 0; mt < 2; ++mt)
        #pragma unroll
        for (int rr = 0; rr < 4; ++rr) {
            const int gr = row0 + mh + mt * 16 + lq * 4 + rr;
            if (gr >= ng) continue;
            const int s = lists[g * BATCH + gr];
            #pragma unroll
            for (int nt = 0; nt < 2; ++nt) {
                const int n = n0 + nh + nt * 16 + lm;
                if (n >= NOUT) continue;
                float x = acc[mt][nt][rr] + bias[(size_t)g * NOUT + n];
                x = (ACT == 0) ? fmaxf(x, 0.f) : tanhf(x);
                if (OUTF32) {
                    Cf[(size_t)s * NOUT + n] = x;
                } else {
                    unsigned short h = f2bf(x);
                    Chi[(size_t)s * NOUT + n] = h;
                    if (SPLIT) Clo[(size_t)s * NOUT + n] = f2bf(x - bf2f(h));
                }
            }
        }
}

// ---------------- host ----------------
template<bool SPLIT>
static void run_all(const float* z, const int* gidx,
                    const float* W1, const float* b1, const float* W2, const float* b2,
                    const float* W3, const float* b3, float* out, char* ws, hipStream_t stream) {
    size_t off = 0;
    auto alloc = [&](size_t bytes) { size_t o = off; off = (off + bytes + 255) & ~255ULL; return o; };
    int*  counts = (int*)(ws + alloc(256));
    int*  lists  = (int*)(ws + alloc((size_t)BATCH * NGEN * 4));
    unsigned short* zhi  = (unsigned short*)(ws + alloc((size_t)BATCH * NZ * 2));
    unsigned short* h1hi = (unsigned short*)(ws + alloc((size_t)BATCH * H1 * 2));
    unsigned short* h2hi = (unsigned short*)(ws + alloc((size_t)BATCH * H2 * 2));
    unsigned short* W1t  = (unsigned short*)(ws + alloc((size_t)NGEN * H1 * NZ * 2));
    unsigned short* W2t  = (unsigned short*)(ws + alloc((size_t)NGEN * H2 * H1 * 2));
    unsigned short* W3t  = (unsigned short*)(ws + alloc((size_t)NGEN * IMGP * H2 * 2));
    unsigned short *zlo = zhi, *h1lo = h1hi, *h2lo = h2hi, *W1tl = W1t, *W2tl = W2t, *W3tl = W3t;
    if (SPLIT) {
        zlo  = (unsigned short*)(ws + alloc((size_t)BATCH * NZ * 2));
        h1lo = (unsigned short*)(ws + alloc((size_t)BATCH * H1 * 2));
        h2lo = (unsigned short*)(ws + alloc((size_t)BATCH * H2 * 2));
        W1tl = (unsigned short*)(ws + alloc((size_t)NGEN * H1 * NZ * 2));
        W2tl = (unsigned short*)(ws + alloc((size_t)NGEN * H2 * H1 * 2));
        W3tl = (unsigned short*)(ws + alloc((size_t)NGEN * IMGP * H2 * 2));
    }

    hipMemsetAsync(counts, 0, 256, stream);
    bucket_kernel<<<dim3(BATCH / 256), dim3(256), 0, stream>>>(gidx, counts, lists);
    split_act<SPLIT><<<dim3((BATCH * NZ) / 256), dim3(256), 0, stream>>>(z, zhi, zlo, BATCH * NZ);
    transpose_split<NZ, H1, H1, SPLIT><<<dim3(NZ / 32, H1 / 32, NGEN), dim3(256), 0, stream>>>(W1, W1t, W1tl);
    transpose_split<H1, H2, H2, SPLIT><<<dim3(H1 / 32, H2 / 32, NGEN), dim3(256), 0, stream>>>(W2, W2t, W2tl);
    transpose_split<H2, IMG, IMGP, SPLIT><<<dim3(H2 / 32, IMGP / 32, NGEN), dim3(256), 0, stream>>>(W3, W3t, W3tl);

    gemm_mfma<NZ, H1, H1, 0, SPLIT, false><<<dim3(BATCH / 64, H1 / 64, NGEN), dim3(256), 0, stream>>>(
        zhi, zlo, W1t, W1tl, b1, h1hi, h1lo, nullptr, counts, lists);
    gemm_mfma<H1, H2, H2, 0, SPLIT, false><<<dim3(BATCH / 64, H2 / 64, NGEN), dim3(256), 0, stream>>>(
        h1hi, h1lo, W2t, W2tl, b2, h2hi, h2lo, nullptr, counts, lists);
    gemm_mfma<H2, IMG, IMGP, 1, SPLIT, true><<<dim3(BATCH / 64, IMGP / 64, NGEN), dim3(256), 0, stream>>>(
        h2hi, h2lo, W3t, W3tl, b3, nullptr, nullptr, out, counts, lists);
}

extern "C" void kernel_launch(void* const* d_in, const int* in_sizes, int n_in,
                              void* d_out, int out_size, void* d_ws, size_t ws_size,
                              hipStream_t stream) {
    const float* z    = (const float*)d_in[0];
    const int*   gidx = (const int*)  d_in[1];
    const float* W1   = (const float*)d_in[2];
    const float* b1   = (const float*)d_in[3];
    const float* W2   = (const float*)d_in[4];
    const float* b2   = (const float*)d_in[5];
    const float* W3   = (const float*)d_in[6];
    const float* b3   = (const float*)d_in[7];
    float* out = (float*)d_out;

    // full split needs ~86 MB; fall back to hi-only bf16 (still under threshold est.) if ws is small
    const size_t need_split = 90ull * 1024 * 1024;
    if (ws_size >= need_split)
        run_all<true >(z, gidx, W1, b1, W2, b2, W3, b3, out, (char*)d_ws, stream);
    else
        run_all<false>(z, gidx, W1, b1, W2, b2, W3, b3, out, (char*)d_ws, stream);
}

// Round 3
// 271.489 us; speedup vs baseline: 2.6558x; 1.5873x over previous
//
#include <hip/hip_runtime.h>
#include <math.h>

#define NZ    128
#define H1    512
#define H2    1024
#define IMG   784
#define IMGP  832
#define BATCH 4096
#define NGEN  10

typedef _Float16 f16;
typedef __attribute__((ext_vector_type(8))) _Float16 half8;
typedef __attribute__((ext_vector_type(4))) float floatx4;

// ---------------- bucket samples by generator ----------------
__global__ void bucket_kernel(const int* __restrict__ g_idx,
                              int* __restrict__ counts,
                              int* __restrict__ lists) {
    int b = blockIdx.x * blockDim.x + threadIdx.x;
    if (b < BATCH) {
        int g = g_idx[b];
        int pos = atomicAdd(&counts[g], 1);
        lists[g * BATCH + pos] = b;
    }
}

// ---------------- f32 -> f16 convert (z) ----------------
__global__ void conv_f16(const float* __restrict__ x, f16* __restrict__ y, int n) {
    int i = blockIdx.x * 256 + threadIdx.x;
    if (i < n) y[i] = (f16)x[i];
}

// ---------------- transpose W: [g][K][N] f32 -> [g][NPAD][K] f16 ----------------
template<int K, int N, int NPAD>
__global__ __launch_bounds__(256)
void transpose_f16(const float* __restrict__ W, f16* __restrict__ Wt) {
    const int g  = blockIdx.z;
    const int k0 = blockIdx.x * 32;
    const int n0 = blockIdx.y * 32;
    __shared__ f16 L[32][36];
    const int t = threadIdx.x;
    {
        const int kk = t >> 3;
        const int nq = (t & 7) * 4;
        float4 v = make_float4(0.f, 0.f, 0.f, 0.f);
        if (n0 + nq < N)   // N % 4 == 0: quads never straddle
            v = *(const float4*)(W + ((size_t)g * K + (k0 + kk)) * N + n0 + nq);
        L[nq + 0][kk] = (f16)v.x;
        L[nq + 1][kk] = (f16)v.y;
        L[nq + 2][kk] = (f16)v.z;
        L[nq + 3][kk] = (f16)v.w;
    }
    __syncthreads();
    {
        const int nn = t >> 3;
        const int kq = (t & 7) * 4;
        *(ushort4*)(Wt + ((size_t)g * NPAD + (n0 + nn)) * K + k0 + kq) =
            *(const ushort4*)&L[nn][kq];
    }
}

// ---------------- weight-stationary grouped GEMM ----------------
// Block: one (m-slice, 32-col n-tile, generator). B-tile [NT][K] resident in
// LDS (row pad +8 f16 -> bank-quad shift of 4 per row: uniform coverage).
// No __syncthreads in the hot loop: waves stream MFMA A-fragments straight
// from global (contiguous 16 B per lane) against LDS-resident B.
// Wave w handles supertiles (64 rows) st = w, w+4, ...; per k-chunk:
// 4 global a-loads + NF ds_read_b128 + 4*NF MFMAs.
template<int K, int NOUT, int NPADB, int NT, int MSPLIT, int ACT, bool OUTF32, int MINW>
__global__ __launch_bounds__(256, MINW)
void gemm_ws(const f16* __restrict__ A, const f16* __restrict__ Wt,
             const float* __restrict__ bias,
             f16* __restrict__ Ch, float* __restrict__ Cf,
             const int* __restrict__ counts, const int* __restrict__ lists) {
    constexpr int KP = K + 8;
    constexpr int NF = NT / 16;
    const int g  = blockIdx.z;
    const int ng = counts[g];
    if (ng <= 0) return;
    const int n0 = blockIdx.y * NT;
    const int m_start = (int)(((long long)blockIdx.x * ng) / MSPLIT);
    const int m_end   = (int)(((long long)(blockIdx.x + 1) * ng) / MSPLIT);
    const int m_len   = m_end - m_start;
    if (m_len <= 0) return;            // block-uniform

    __shared__ f16 Bs[NT * KP];
    const int tid = threadIdx.x;

    // stage B tile once: NT rows x K f16, 16 B per thread-iteration
    #pragma unroll
    for (int i = tid; i < NT * (K / 8); i += 256) {
        const int row = i / (K / 8);
        const int kq  = (i % (K / 8)) * 8;
        *(half8*)&Bs[row * KP + kq] =
            *(const half8*)(Wt + ((size_t)g * NPADB + n0 + row) * K + kq);
    }
    __syncthreads();

    const int lane = tid & 63, w = tid >> 6;
    const int lm = lane & 15, lq = lane >> 4;

    float bs[NF];
    #pragma unroll
    for (int nf = 0; nf < NF; ++nf) {
        const int n = n0 + nf * 16 + lm;
        bs[nf] = (n < NOUT) ? bias[(size_t)g * NOUT + n] : 0.f;
    }

    const int* lst = lists + g * BATCH;

    for (int st = w; st * 64 < m_len; st += 4) {
        const int m0 = m_start + st * 64;
        const f16* ap[4];
        #pragma unroll
        for (int mt = 0; mt < 4; ++mt) {
            const int r = m0 + mt * 16 + lm;
            const int s = lst[min(r, ng - 1)];
            ap[mt] = A + (size_t)s * K + lq * 8;
        }

        floatx4 acc[4][NF] = {};
        #pragma unroll
        for (int kc = 0; kc < K / 32; ++kc) {
            half8 bb[NF];
            #pragma unroll
            for (int nf = 0; nf < NF; ++nf)
                bb[nf] = *(const half8*)&Bs[(nf * 16 + lm) * KP + kc * 32 + lq * 8];
            #pragma unroll
            for (int mt = 0; mt < 4; ++mt) {
                const half8 ah = *(const half8*)(ap[mt] + kc * 32);
                #pragma unroll
                for (int nf = 0; nf < NF; ++nf)
                    acc[mt][nf] = __builtin_amdgcn_mfma_f32_16x16x32_f16(
                        ah, bb[nf], acc[mt][nf], 0, 0, 0);
            }
        }

        // epilogue: C/D layout col = lane&15, row = (lane>>4)*4 + reg
        #pragma unroll
        for (int mt = 0; mt < 4; ++mt)
            #pragma unroll
            for (int rr = 0; rr < 4; ++rr) {
                const int row = m0 + mt * 16 + lq * 4 + rr;
                if (row >= m_end) continue;
                const int s = lst[row];
                #pragma unroll
                for (int nf = 0; nf < NF; ++nf) {
                    const int n = n0 + nf * 16 + lm;
                    if (n >= NOUT) continue;
                    float x = acc[mt][nf][rr] + bs[nf];
                    if (ACT == 0) {
                        x = fmaxf(x, 0.f);
                    } else {
                        // tanh(x) = 1 - 2/(exp(2x)+1): inf-safe, monotone
                        const float e = __expf(2.f * x);
                        x = 1.f - 2.f / (e + 1.f);
                    }
                    if (OUTF32) Cf[(size_t)s * NOUT + n] = x;
                    else        Ch[(size_t)s * NOUT + n] = (f16)x;
                }
            }
    }
}

extern "C" void kernel_launch(void* const* d_in, const int* in_sizes, int n_in,
                              void* d_out, int out_size, void* d_ws, size_t ws_size,
                              hipStream_t stream) {
    const float* z    = (const float*)d_in[0];
    const int*   gidx = (const int*)  d_in[1];
    const float* W1   = (const float*)d_in[2];
    const float* b1   = (const float*)d_in[3];
    const float* W2   = (const float*)d_in[4];
    const float* b2   = (const float*)d_in[5];
    const float* W3   = (const float*)d_in[6];
    const float* b3   = (const float*)d_in[7];
    float* out = (float*)d_out;

    char* ws = (char*)d_ws;
    size_t off = 0;
    auto alloc = [&](size_t bytes) { size_t o = off; off = (off + bytes + 255) & ~255ULL; return o; };
    int* counts = (int*)(ws + alloc(256));
    int* lists  = (int*)(ws + alloc((size_t)BATCH * NGEN * 4));
    f16* zh  = (f16*)(ws + alloc((size_t)BATCH * NZ * 2));
    f16* h1  = (f16*)(ws + alloc((size_t)BATCH * H1 * 2));
    f16* h2  = (f16*)(ws + alloc((size_t)BATCH * H2 * 2));
    f16* W1t = (f16*)(ws + alloc((size_t)NGEN * H1 * NZ * 2));
    f16* W2t = (f16*)(ws + alloc((size_t)NGEN * H2 * H1 * 2));
    f16* W3t = (f16*)(ws + alloc((size_t)NGEN * IMGP * H2 * 2));

    hipMemsetAsync(counts, 0, 256, stream);
    bucket_kernel<<<dim3(BATCH / 256), dim3(256), 0, stream>>>(gidx, counts, lists);
    conv_f16<<<dim3((BATCH * NZ) / 256), dim3(256), 0, stream>>>(z, zh, BATCH * NZ);
    transpose_f16<NZ, H1, H1><<<dim3(NZ / 32, H1 / 32, NGEN), dim3(256), 0, stream>>>(W1, W1t);
    transpose_f16<H1, H2, H2><<<dim3(H1 / 32, H2 / 32, NGEN), dim3(256), 0, stream>>>(W2, W2t);
    transpose_f16<H2, IMG, IMGP><<<dim3(H2 / 32, IMGP / 32, NGEN), dim3(256), 0, stream>>>(W3, W3t);

    // L1: K=128  LDS 8.7 KB,  grid (2,16,10)=320 blocks, 1 supertile/wave
    gemm_ws<NZ, H1, H1, 32, 2, 0, false, 4>
        <<<dim3(2, H1 / 32, NGEN), dim3(256), 0, stream>>>(
            zh, W1t, b1, h1, nullptr, counts, lists);
    // L2: K=512  LDS 33.3 KB (4 blk/CU), grid (2,32,10)=640 blocks
    gemm_ws<H1, H2, H2, 32, 2, 0, false, 4>
        <<<dim3(2, H2 / 32, NGEN), dim3(256), 0, stream>>>(
            h1, W2t, b2, h2, nullptr, counts, lists);
    // L3: K=1024 LDS 66 KB (2 blk/CU), grid (1,26,10)=260 blocks, tanh, f32 out
    gemm_ws<H2, IMG, IMGP, 32, 1, 1, true, 2>
        <<<dim3(1, IMGP / 32, NGEN), dim3(256), 0, stream>>>(
            h2, W3t, b3, nullptr, out, counts, lists);
}